// Round 2
// baseline (701.079 us; speedup 1.0000x reference)
//
#include <hip/hip_runtime.h>

typedef unsigned short u16;
typedef __attribute__((ext_vector_type(4))) float f32x4;
typedef __attribute__((ext_vector_type(8))) short short8;

#define MFMA16(a,b,c) __builtin_amdgcn_mfma_f32_16x16x32_bf16((a),(b),(c),0,0,0)

__device__ __forceinline__ u16 f2bf(float f){
  unsigned u = __float_as_uint(f);
  u += 0x7fffu + ((u>>16)&1u);
  return (u16)(u>>16);
}
__device__ __forceinline__ float bf2f(u16 s){ return __uint_as_float(((unsigned)s)<<16); }

__device__ __forceinline__ void glds16(const void* g, void* l){
  __builtin_amdgcn_global_load_lds(
    (const __attribute__((address_space(1))) unsigned int*)g,
    (__attribute__((address_space(3))) unsigned int*)l, 16, 0, 0);
}

// ---------------- prep kernels ----------------

// hidden (8,388,608 floats) -> Hh, Hl bf16 (split)
__global__ __launch_bounds__(256) void k_split_hidden(const float4* __restrict__ H,
    u16* __restrict__ Hh, u16* __restrict__ Hl){
  int i = blockIdx.x*256 + threadIdx.x;   // 2,097,152 float4s
  float4 v = H[i];
  u16 h0=f2bf(v.x), h1=f2bf(v.y), h2=f2bf(v.z), h3=f2bf(v.w);
  ushort4 hi = make_ushort4(h0,h1,h2,h3);
  ushort4 lo = make_ushort4(f2bf(v.x-bf2f(h0)), f2bf(v.y-bf2f(h1)),
                            f2bf(v.z-bf2f(h2)), f2bf(v.w-bf2f(h3)));
  *(ushort4*)(Hh + (size_t)i*4) = hi;
  *(ushort4*)(Hl + (size_t)i*4) = lo;
}

// transpose one weight matrix to B^T layout [n][k]; optional lo part
__global__ __launch_bounds__(256) void k_prep_w1(const float* __restrict__ W,
    u16* __restrict__ hiT, u16* __restrict__ loT, int write_lo){
  __shared__ float tile[64][65];
  int k0 = blockIdx.x*64, n0 = blockIdx.y*64;
  int t = threadIdx.x;
  #pragma unroll 4
  for (int i=0;i<16;i++){
    int idx = t + i*256; int r = idx>>6, c = idx&63;
    tile[r][c] = W[(size_t)(k0+r)*2048 + n0 + c];
  }
  __syncthreads();
  #pragma unroll 4
  for (int i=0;i<16;i++){
    int idx = t + i*256; int r = idx>>6, c = idx&63;   // r -> n, c -> k
    float v = tile[c][r];
    u16 hi = f2bf(v);
    size_t o = (size_t)(n0+r)*2048 + k0 + c;
    hiT[o] = hi;
    if (write_lo) loT[o] = f2bf(v - bf2f(hi));
  }
}

// cos/sin tables: [2048][64] fp32
__global__ __launch_bounds__(256) void k_rope_tab(const int* __restrict__ pos,
    float* __restrict__ ct, float* __restrict__ st){
  int i = blockIdx.x*256 + threadIdx.x;   // < 131072
  int s = i>>6, j = i&63;
  float p = (float)pos[s];
  float inv = exp2f(-(float)j * 0.20762050593046014f);  // log2(10000)/64
  float a = p*inv;
  ct[i] = cosf(a); st[i] = sinf(a);
}

// ---------------- Q/K GEMM, split precision, epilogue writes split (bh,s,d) ----------------
// O = A*B^T with A = Ah+Al, B = Bh+Bl, dropping Al*Bl.
__global__ __launch_bounds__(256) void k_gemm_split(
    const u16* __restrict__ Ah, const u16* __restrict__ Al,
    const u16* __restrict__ Bh, const u16* __restrict__ Bl,
    u16* __restrict__ Oh, u16* __restrict__ Ol)
{
  __shared__ __align__(16) u16 lAh[128*32], lAl[128*32], lBh[128*32], lBl[128*32];
  int m0 = blockIdx.x*128, n0 = blockIdx.y*128;
  int tid = threadIdx.x, lane = tid&63, w = tid>>6;
  int wr = w>>1, wc = w&1, g = lane>>4, r = lane&15;
  f32x4 acc[4][4];
  #pragma unroll
  for (int i=0;i<4;i++)
    #pragma unroll
    for (int j=0;j<4;j++)
      #pragma unroll
      for (int e=0;e<4;e++) acc[i][j][e]=0.f;

  for (int k0=0;k0<2048;k0+=32){
    __syncthreads();
    #pragma unroll
    for (int c=0;c<2;c++){
      int off = (w*2+c)*1024 + lane*16;
      int row = off>>6, colb = off&63;
      size_t ga = ((size_t)(m0+row)*2048 + k0)*2 + colb;
      size_t gb = ((size_t)(n0+row)*2048 + k0)*2 + colb;
      int lo = (w*2+c)*1024;
      glds16((const char*)Ah + ga, (char*)lAh + lo);
      glds16((const char*)Bh + gb, (char*)lBh + lo);
      glds16((const char*)Al + ga, (char*)lAl + lo);
      glds16((const char*)Bl + gb, (char*)lBl + lo);
    }
    asm volatile("s_waitcnt vmcnt(0)" ::: "memory");
    __syncthreads();
    short8 ah[4], al[4];
    #pragma unroll
    for (int mi=0;mi<4;mi++){
      int row = wr*64 + mi*16 + r;
      ah[mi] = *(const short8*)((const char*)lAh + row*64 + g*16);
      al[mi] = *(const short8*)((const char*)lAl + row*64 + g*16);
    }
    #pragma unroll
    for (int ni=0;ni<4;ni++){
      int row = wc*64 + ni*16 + r;
      short8 b_h = *(const short8*)((const char*)lBh + row*64 + g*16);
      short8 b_l = *(const short8*)((const char*)lBl + row*64 + g*16);
      #pragma unroll
      for (int mi=0;mi<4;mi++){
        acc[mi][ni] = MFMA16(ah[mi], b_h, acc[mi][ni]);
        acc[mi][ni] = MFMA16(ah[mi], b_l, acc[mi][ni]);
        acc[mi][ni] = MFMA16(al[mi], b_h, acc[mi][ni]);
      }
    }
  }
  // epilogue: split hi/lo, store at (bh, s, d) address
  #pragma unroll
  for (int mi=0;mi<4;mi++){
    #pragma unroll
    for (int rr=0;rr<4;rr++){
      int m = m0 + wr*64 + mi*16 + g*4 + rr;
      int b = m>>11, s = m&2047;
      #pragma unroll
      for (int ni=0;ni<4;ni++){
        int n = n0 + wc*64 + ni*16 + r;
        int h = n>>7, d = n&127;
        size_t o = (((size_t)((b<<4)+h)*2048 + s)<<7) + d;
        float v = acc[mi][ni][rr];
        u16 hi = f2bf(v);
        Oh[o] = hi;
        Ol[o] = f2bf(v - bf2f(hi));
      }
    }
  }
}

// ---------------- V GEMM, plain bf16, (b*s, h*d) layout ----------------
__global__ __launch_bounds__(256) void k_gemm_plain_bf(
    const u16* __restrict__ Ah, const u16* __restrict__ Bh, u16* __restrict__ O)
{
  __shared__ __align__(16) u16 lA[128*32], lB[128*32];
  int m0 = blockIdx.x*128, n0 = blockIdx.y*128;
  int tid = threadIdx.x, lane = tid&63, w = tid>>6;
  int wr = w>>1, wc = w&1, g = lane>>4, r = lane&15;
  f32x4 acc[4][4];
  #pragma unroll
  for (int i=0;i<4;i++)
    #pragma unroll
    for (int j=0;j<4;j++)
      #pragma unroll
      for (int e=0;e<4;e++) acc[i][j][e]=0.f;
  for (int k0=0;k0<2048;k0+=32){
    __syncthreads();
    #pragma unroll
    for (int c=0;c<2;c++){
      int off = (w*2+c)*1024 + lane*16;
      int row = off>>6, colb = off&63;
      size_t ga = ((size_t)(m0+row)*2048 + k0)*2 + colb;
      size_t gb = ((size_t)(n0+row)*2048 + k0)*2 + colb;
      int lo = (w*2+c)*1024;
      glds16((const char*)Ah + ga, (char*)lA + lo);
      glds16((const char*)Bh + gb, (char*)lB + lo);
    }
    asm volatile("s_waitcnt vmcnt(0)" ::: "memory");
    __syncthreads();
    short8 af[4];
    #pragma unroll
    for (int mi=0;mi<4;mi++){
      int row = wr*64 + mi*16 + r;
      af[mi] = *(const short8*)((const char*)lA + row*64 + g*16);
    }
    #pragma unroll
    for (int ni=0;ni<4;ni++){
      int row = wc*64 + ni*16 + r;
      short8 b8 = *(const short8*)((const char*)lB + row*64 + g*16);
      #pragma unroll
      for (int mi=0;mi<4;mi++)
        acc[mi][ni] = MFMA16(af[mi], b8, acc[mi][ni]);
    }
  }
  #pragma unroll
  for (int mi=0;mi<4;mi++){
    #pragma unroll
    for (int rr=0;rr<4;rr++){
      int row = m0 + wr*64 + mi*16 + g*4 + rr;
      #pragma unroll
      for (int ni=0;ni<4;ni++){
        int col = n0 + wc*64 + ni*16 + r;
        O[(size_t)row*2048+col] = f2bf(acc[mi][ni][rr]);
      }
    }
  }
}

// ---------------- in-place RoPE on split (bh,s,d) arrays ----------------
__global__ __launch_bounds__(256) void k_rope_ip(u16* __restrict__ Xh, u16* __restrict__ Xl,
    const float* __restrict__ ct, const float* __restrict__ st){
  int i = blockIdx.x*256 + threadIdx.x;   // < 4,194,304 = 32bh * 2048s * 64 pairs
  int row = i>>6, j = i&63;               // row = bh*2048 + s
  int s = row & 2047;
  size_t base = (size_t)row*128;
  float x1 = bf2f(Xh[base+j])    + bf2f(Xl[base+j]);
  float x2 = bf2f(Xh[base+64+j]) + bf2f(Xl[base+64+j]);
  float c = ct[s*64+j], sn = st[s*64+j];
  float o1 = x1*c - x2*sn, o2 = x2*c + x1*sn;
  u16 a1 = f2bf(o1), a2 = f2bf(o2);
  Xh[base+j]    = a1; Xl[base+j]    = f2bf(o1 - bf2f(a1));
  Xh[base+64+j] = a2; Xl[base+64+j] = f2bf(o2 - bf2f(a2));
}

// V (b*s, h*d) bf16 -> VT (bh, d, s) bf16
__global__ __launch_bounds__(256) void k_vt(const u16* __restrict__ Vb, u16* __restrict__ VT){
  __shared__ u16 tile[128][129];
  int bh = blockIdx.y, b = bh>>4, h = bh&15;
  int s0 = blockIdx.x*128;
  int t = threadIdx.x;
  #pragma unroll 4
  for (int i=0;i<16;i++){
    int idx = i*1024 + t*4; int srow = idx>>7, c = idx&127;
    const u16* gp = Vb + ((size_t)(b*2048+s0+srow))*2048 + h*128 + c;
    ushort4 v = *(const ushort4*)gp;
    tile[srow][c]=v.x; tile[srow][c+1]=v.y; tile[srow][c+2]=v.z; tile[srow][c+3]=v.w;
  }
  __syncthreads();
  #pragma unroll 4
  for (int i=0;i<16;i++){
    int idx = i*1024 + t*4; int drow = idx>>7, s = idx&127;
    ushort4 v = make_ushort4(tile[s][drow], tile[s+1][drow], tile[s+2][drow], tile[s+3][drow]);
    *(ushort4*)(VT + ((size_t)(bh*128+drow))*2048 + s0 + s) = v;
  }
}

// ---------------- flash attention ----------------
// grid (32 q-tiles, 32 bh), 4 waves x 16 q-rows, KVBLK=64
__global__ __launch_bounds__(256) void k_attn(
  const u16* __restrict__ Qh, const u16* __restrict__ Ql,
  const u16* __restrict__ Kh, const u16* __restrict__ Kl,
  const u16* __restrict__ VT, u16* __restrict__ AO)
{
  __shared__ __align__(16) u16 lKh[64*128], lKl[64*128], lVT[128*64];
  __shared__ __align__(16) u16 lP[4*16*72];
  int bh = blockIdx.y, q0 = blockIdx.x*64;
  int tid = threadIdx.x, lane = tid&63, w = tid>>6;
  int g = lane>>4, r = lane&15;
  const float SC = 0.12751878329866064f;  // log2(e)/sqrt(128)
  short8 qh[4], ql[4];
  {
    size_t qb = ((size_t)bh*2048 + q0 + w*16 + r)*128;
    #pragma unroll
    for (int ks=0;ks<4;ks++){
      qh[ks] = *(const short8*)(Qh + qb + ks*32 + g*8);
      ql[ks] = *(const short8*)(Ql + qb + ks*32 + g*8);
    }
  }
  f32x4 o[8];
  #pragma unroll
  for (int i=0;i<8;i++)
    #pragma unroll
    for (int e=0;e<4;e++) o[i][e]=0.f;
  float mrow[4] = {-3.0e38f,-3.0e38f,-3.0e38f,-3.0e38f};
  float lrow[4] = {0.f,0.f,0.f,0.f};
  size_t kb = (size_t)bh*2048*128;
  size_t vbase = (size_t)bh*128*2048;

  for (int kv0=0;kv0<2048;kv0+=64){
    __syncthreads();
    #pragma unroll
    for (int c=0;c<4;c++){
      int off = (w*4+c)*1024 + lane*16;
      int lo = (w*4+c)*1024;
      int row = off>>8, ch = (off>>4)&15;
      int chs = (ch&8)|((ch^row)&7);                        // pre-swizzled source chunk
      size_t gk = (kb + (size_t)(kv0+row)*128)*2 + chs*16;
      glds16((const char*)Kh + gk, (char*)lKh + lo);
      glds16((const char*)Kl + gk, (char*)lKl + lo);
      int rowd = off>>7, ch2 = (off>>4)&7;
      int chs2 = (ch2^rowd)&7;
      size_t gv = (vbase + (size_t)rowd*2048 + kv0)*2 + chs2*16;
      glds16((const char*)VT + gv, (char*)lVT + lo);
    }
    asm volatile("s_waitcnt vmcnt(0)" ::: "memory");
    __syncthreads();

    f32x4 s4[4];
    #pragma unroll
    for (int i=0;i<4;i++)
      #pragma unroll
      for (int e=0;e<4;e++) s4[i][e]=0.f;
    #pragma unroll
    for (int ks=0;ks<4;ks++){
      #pragma unroll
      for (int ni=0;ni<4;ni++){
        int kvr = ni*16 + r;
        int ch = ks*4 + g;
        int chs = (ch&8)|((ch^kvr)&7);                      // swizzled read
        short8 kh8 = *(const short8*)((const char*)lKh + kvr*256 + chs*16);
        short8 kl8 = *(const short8*)((const char*)lKl + kvr*256 + chs*16);
        s4[ni] = MFMA16(qh[ks], kh8, s4[ni]);
        s4[ni] = MFMA16(qh[ks], kl8, s4[ni]);
        s4[ni] = MFMA16(ql[ks], kh8, s4[ni]);
      }
    }
    // online softmax (rows = g*4+rr, shared across the 16-lane group)
    float pm[4], f[4], rs[4];
    #pragma unroll
    for (int rr=0;rr<4;rr++){
      float m = fmaxf(fmaxf(s4[0][rr], s4[1][rr]), fmaxf(s4[2][rr], s4[3][rr]));
      m = fmaxf(m, __shfl_xor(m,1));
      m = fmaxf(m, __shfl_xor(m,2));
      m = fmaxf(m, __shfl_xor(m,4));
      m = fmaxf(m, __shfl_xor(m,8));
      pm[rr]=m;
    }
    #pragma unroll
    for (int rr=0;rr<4;rr++){
      float mn = fmaxf(mrow[rr], pm[rr]);
      f[rr] = exp2f((mrow[rr]-mn)*SC);
      mrow[rr]=mn; lrow[rr]*=f[rr];
    }
    #pragma unroll
    for (int nd=0;nd<8;nd++)
      #pragma unroll
      for (int rr=0;rr<4;rr++) o[nd][rr] *= f[rr];
    #pragma unroll
    for (int rr=0;rr<4;rr++) rs[rr]=0.f;
    #pragma unroll
    for (int ni=0;ni<4;ni++){
      #pragma unroll
      for (int rr=0;rr<4;rr++){
        float p = exp2f((s4[ni][rr]-mrow[rr])*SC);
        rs[rr] += p;
        lP[w*1152 + (g*4+rr)*72 + ni*16 + r] = f2bf(p);
      }
    }
    #pragma unroll
    for (int rr=0;rr<4;rr++){
      float x = rs[rr];
      x += __shfl_xor(x,1); x += __shfl_xor(x,2);
      x += __shfl_xor(x,4); x += __shfl_xor(x,8);
      lrow[rr] += x;
    }
    // PV
    #pragma unroll
    for (int ks2=0;ks2<2;ks2++){
      short8 pa = *(const short8*)((const char*)lP + w*2304 + r*144 + ks2*64 + g*16);
      #pragma unroll
      for (int nd=0;nd<8;nd++){
        int dr = nd*16 + r;
        int chs = ((ks2*4+g)^dr)&7;
        short8 v8 = *(const short8*)((const char*)lVT + dr*128 + chs*16);
        o[nd] = MFMA16(pa, v8, o[nd]);
      }
    }
  }
  int b = bh>>4, h = bh&15;
  #pragma unroll
  for (int rr=0;rr<4;rr++){
    float inv = 1.0f/lrow[rr];
    int row = b*2048 + q0 + w*16 + g*4 + rr;
    #pragma unroll
    for (int nd=0;nd<8;nd++){
      int col = h*128 + nd*16 + r;
      AO[(size_t)row*2048 + col] = f2bf(o[nd][rr]*inv);
    }
  }
}

// ---------------- out projection (bf16 A,B -> fp32 C) ----------------
__global__ __launch_bounds__(256) void k_gemm_out(
    const u16* __restrict__ A, const u16* __restrict__ Bt, float* __restrict__ C)
{
  __shared__ __align__(16) u16 lA[128*32], lB[128*32];
  int m0 = blockIdx.x*128, n0 = blockIdx.y*128;
  int tid = threadIdx.x, lane = tid&63, w = tid>>6;
  int wr = w>>1, wc = w&1, g = lane>>4, r = lane&15;
  f32x4 acc[4][4];
  #pragma unroll
  for (int i=0;i<4;i++)
    #pragma unroll
    for (int j=0;j<4;j++)
      #pragma unroll
      for (int e=0;e<4;e++) acc[i][j][e]=0.f;
  for (int k0=0;k0<2048;k0+=32){
    __syncthreads();
    #pragma unroll
    for (int c=0;c<2;c++){
      int off = (w*2+c)*1024 + lane*16;
      int row = off>>6, colb = off&63;
      size_t ga = ((size_t)(m0+row)*2048 + k0)*2 + colb;
      size_t gb = ((size_t)(n0+row)*2048 + k0)*2 + colb;
      int lo = (w*2+c)*1024;
      glds16((const char*)A + ga, (char*)lA + lo);
      glds16((const char*)Bt + gb, (char*)lB + lo);
    }
    asm volatile("s_waitcnt vmcnt(0)" ::: "memory");
    __syncthreads();
    short8 af[4];
    #pragma unroll
    for (int mi=0;mi<4;mi++){
      int row = wr*64 + mi*16 + r;
      af[mi] = *(const short8*)((const char*)lA + row*64 + g*16);
    }
    #pragma unroll
    for (int ni=0;ni<4;ni++){
      int row = wc*64 + ni*16 + r;
      short8 b8 = *(const short8*)((const char*)lB + row*64 + g*16);
      #pragma unroll
      for (int mi=0;mi<4;mi++)
        acc[mi][ni] = MFMA16(af[mi], b8, acc[mi][ni]);
    }
  }
  #pragma unroll
  for (int mi=0;mi<4;mi++){
    #pragma unroll
    for (int rr=0;rr<4;rr++){
      int row = m0 + wr*64 + mi*16 + g*4 + rr;
      #pragma unroll
      for (int ni=0;ni<4;ni++){
        int col = n0 + wc*64 + ni*16 + r;
        C[(size_t)row*2048+col] = acc[mi][ni][rr];
      }
    }
  }
}

extern "C" void kernel_launch(void* const* d_in, const int* in_sizes, int n_in,
                              void* d_out, int out_size, void* d_ws, size_t ws_size,
                              hipStream_t stream){
  const float* Hsrc = (const float*)d_in[0];
  const int*   pids = (const int*)d_in[1];
  const float* Wq   = (const float*)d_in[2];
  const float* Wk   = (const float*)d_in[3];
  const float* Wv   = (const float*)d_in[4];
  const float* Wo   = (const float*)d_in[5];
  float* out = (float*)d_out;

  // ---- workspace layout (peak 135,266,304 bytes) ----
  // NOTE sizes: Q/K/V tensors are 4096x2048 = 8,388,608 ELEMENTS = 16,777,216 BYTES bf16.
  char* p = (char*)d_ws;
  u16* Hh  = (u16*)(p);                 // 16,777,216  (later reused as VT)
  u16* Hl  = (u16*)(p +  16777216);     // 16,777,216  (later reused as AO)
  u16* Wbh = (u16*)(p +  33554432);     //  8,388,608  (sequential Wq/Wk/Wv/Wo hi)
  u16* Wbl = (u16*)(p +  41943040);     //  8,388,608  (Wq/Wk lo)
  u16* Qsh = (u16*)(p +  50331648);     // 16,777,216  Q hi, (bh,s,d)
  u16* Qsl = (u16*)(p +  67108864);     // 16,777,216  Q lo
  u16* Ksh = (u16*)(p +  83886080);     // 16,777,216  K hi
  u16* Ksl = (u16*)(p + 100663296);     // 16,777,216  K lo
  u16* Vb  = (u16*)(p + 117440512);     // 16,777,216  V bf16, (b*s, h*d)
  float* ct = (float*)(p + 134217728);  //    524,288
  float* st = (float*)(p + 134742016);  //    524,288
  u16* VT = Hh;                         // alias: Hh dead after last GEMM
  u16* AO = Hl;                         // alias: Hl dead after last GEMM

  k_split_hidden<<<8192,256,0,stream>>>((const float4*)Hsrc, Hh, Hl);
  k_rope_tab<<<512,256,0,stream>>>(pids, ct, st);

  k_prep_w1<<<dim3(32,32),256,0,stream>>>(Wq, Wbh, Wbl, 1);
  k_gemm_split<<<dim3(32,16),256,0,stream>>>(Hh, Hl, Wbh, Wbl, Qsh, Qsl);
  k_prep_w1<<<dim3(32,32),256,0,stream>>>(Wk, Wbh, Wbl, 1);
  k_gemm_split<<<dim3(32,16),256,0,stream>>>(Hh, Hl, Wbh, Wbl, Ksh, Ksl);
  k_prep_w1<<<dim3(32,32),256,0,stream>>>(Wv, Wbh, Wbl, 0);
  k_gemm_plain_bf<<<dim3(32,16),256,0,stream>>>(Hh, Wbh, Vb);

  k_vt<<<dim3(16,32),256,0,stream>>>(Vb, VT);            // Hh region now VT
  k_rope_ip<<<16384,256,0,stream>>>(Qsh, Qsl, ct, st);
  k_rope_ip<<<16384,256,0,stream>>>(Ksh, Ksl, ct, st);
  k_prep_w1<<<dim3(32,32),256,0,stream>>>(Wo, Wbh, Wbl, 0);

  k_attn<<<dim3(32,32),256,0,stream>>>(Qsh, Qsl, Ksh, Ksl, VT, AO);
  k_gemm_out<<<dim3(32,16),256,0,stream>>>(AO, Wbh, out);
}